// Round 2
// baseline (73.369 us; speedup 1.0000x reference)
//
#include <hip/hip_runtime.h>

#define NATOMS 512
#define N2 (NATOMS*NATOMS)
#define NKPT 32
#define NPOLY 12
#define NSP 4
#define NSMAX 96           // K padded to 3 x 32
#define KSTR 104           // LDS row stride in bf16 elems (52 dwords; (20r+4g)%32 -> 2-way, free)
#define TI 4
#define TJ 64
#define NTHREADS 256

typedef __attribute__((ext_vector_type(8))) short bf16x8;
typedef __attribute__((ext_vector_type(4))) float f32x4;

static __device__ __forceinline__ unsigned short f2bf(float f) {
    union { float f; unsigned u; } x; x.f = f;
    unsigned r = x.u + 0x7FFFu + ((x.u >> 16) & 1u);   // RNE bf16
    return (unsigned short)(r >> 16);
}

__global__ __launch_bounds__(NTHREADS, 2)
void dftb_mfma(const float* __restrict__ positions,
               const int* __restrict__ species,
               const float* __restrict__ kpoints,
               const float* __restrict__ param,
               const float* __restrict__ onsite,
               const float* __restrict__ shifts,
               float* __restrict__ out, int ns)
{
    __shared__ unsigned short Vt[NTHREADS][KSTR];   // A: V[ij_local][s] bf16
    __shared__ unsigned short Tt[64][KSTR];         // B^T: T[kcol][s] bf16 (0..31 cos, 32..63 sin)
    __shared__ float4 sh4[NSMAX];
    __shared__ float cpar[NSP*NSP*NPOLY];

    const int tid = threadIdx.x;
    const int bi = blockIdx.x >> 3;     // 128 i-tiles of 4
    const int bj = blockIdx.x & 7;      // 8 j-tiles of 64
    if (ns > NSMAX) ns = NSMAX;

    // ---- phase 0: zero B table (incl. K-padding), stage shifts + params ----
    for (int idx = tid; idx < 64*(KSTR/2); idx += NTHREADS)
        ((unsigned*)Tt)[idx] = 0u;
    for (int idx = tid; idx < NSMAX; idx += NTHREADS) {
        if (idx < ns) sh4[idx] = make_float4(shifts[idx*3], shifts[idx*3+1], shifts[idx*3+2], 0.f);
        else          sh4[idx] = make_float4(0.f, 0.f, 0.f, 0.f);
    }
    for (int idx = tid; idx < NSP*NSP*NPOLY; idx += NTHREADS)
        cpar[idx] = param[idx];
    __syncthreads();

    // ---- phase 1a: phase table  T[k][s]=cos(ang), T[k+32][s]=sin(ang) ----
    // ang = 2*pi * (kpoints[k]*0.2) . shifts[s]   (lattice = diag(5))
    for (int idx = tid; idx < ns*NKPT; idx += NTHREADS) {
        int s = idx >> 5, k = idx & 31;
        float4 sh = sh4[s];
        float d = (kpoints[k*3]*0.2f*sh.x + kpoints[k*3+1]*0.2f*sh.y) + kpoints[k*3+2]*0.2f*sh.z;
        float sn, cs;
        sincosf(6.283185307179586f * d, &sn, &cs);
        Tt[k][s]      = f2bf(cs);
        Tt[k+32][s]   = f2bf(sn);
    }

    // ---- phase 1b: V rows (fp32 gate/poly exactly as before, then bf16) ----
    {
        const int li = tid >> 6, lj = tid & 63;
        const int i = bi*TI + li, j = bj*TJ + lj;
        const float pix = positions[i*3], piy = positions[i*3+1], piz = positions[i*3+2];
        const float pjx = positions[j*3], pjy = positions[j*3+1], pjz = positions[j*3+2];
        const int si = species[i], sj = species[j];
        float c[NPOLY];
        #pragma unroll
        for (int q = 0; q < NPOLY; ++q) c[q] = cpar[(si*NSP + sj)*NPOLY + q];
        unsigned* vrow = (unsigned*)&Vt[tid][0];
        for (int s2 = 0; s2 < NSMAX/2; ++s2) {
            float v01[2] = {0.f, 0.f};
            #pragma unroll
            for (int h = 0; h < 2; ++h) {
                int s = 2*s2 + h;
                if (s < ns) {
                    float4 sh = sh4[s];
                    // numpy order: (pj + shift) - pi ; (x^2 + y^2) + z^2, no FMA contraction
                    float dx = (pjx + sh.x) - pix;
                    float dy = (pjy + sh.y) - piy;
                    float dz = (pjz + sh.z) - piz;
                    float dr2 = (__fmul_rn(dx,dx) + __fmul_rn(dy,dy)) + __fmul_rn(dz,dz);
                    float dr = sqrtf(dr2);
                    bool ok = (dr > 0.1f) && (dr <= 6.0f);
                    if (__ballot(ok) != 0ULL) {
                        float x = dr * 1.8897261258369282f;
                        float y = c[NPOLY-1];
                        #pragma unroll
                        for (int q = NPOLY-2; q >= 0; --q) y = fmaf(y, x, c[q]);
                        v01[h] = ok ? y : 0.f;
                    }
                }
            }
            vrow[s2] = (unsigned)f2bf(v01[0]) | ((unsigned)f2bf(v01[1]) << 16);
        }
    }
    __syncthreads();

    // ---- phase 2: MFMA  D[ij, kcol] = sum_s V[ij,s] * T[kcol,s] ----
    const int w = tid >> 6, lane = tid & 63;
    const int r16 = lane & 15, g = lane >> 4;

    // B-frags: lane holds B[k=s-block (g*8+e)][n=kcol (r16)] -> contiguous 8 bf16 along s
    bf16x8 Bf[4][3];
    #pragma unroll
    for (int nf = 0; nf < 4; ++nf)
        #pragma unroll
        for (int kf = 0; kf < 3; ++kf)
            Bf[nf][kf] = *(const bf16x8*)&Tt[nf*16 + r16][kf*32 + g*8];

    const int irow = bi*TI + w;                 // this wave's global i (fixed)
    const float ons = onsite[species[irow]];

    #pragma unroll
    for (int mf = 0; mf < 4; ++mf) {
        const int arow = w*64 + mf*16 + r16;    // A row = local ij; lane m = r16
        bf16x8 A0 = *(const bf16x8*)&Vt[arow][      g*8];
        bf16x8 A1 = *(const bf16x8*)&Vt[arow][32 +  g*8];
        bf16x8 A2 = *(const bf16x8*)&Vt[arow][64 +  g*8];
        #pragma unroll
        for (int nf = 0; nf < 4; ++nf) {
            f32x4 acc = {0.f, 0.f, 0.f, 0.f};
            acc = __builtin_amdgcn_mfma_f32_16x16x32_bf16(A0, Bf[nf][0], acc, 0, 0, 0);
            acc = __builtin_amdgcn_mfma_f32_16x16x32_bf16(A1, Bf[nf][1], acc, 0, 0, 0);
            acc = __builtin_amdgcn_mfma_f32_16x16x32_bf16(A2, Bf[nf][2], acc, 0, 0, 0);
            // C/D layout (verified m89): col = lane&15, row = (lane>>4)*4 + reg
            const int kcol = nf*16 + r16;                   // 0..31 -> Hr plane, 32..63 -> Hi plane
            const int jb   = bj*TJ + mf*16 + g*4;           // 4 consecutive j per lane
            float4 v; v.x = acc[0]; v.y = acc[1]; v.z = acc[2]; v.w = acc[3];
            if (kcol < 32) {                                // onsite on Hr diagonal
                int q = irow - jb;
                if (q >= 0 && q < 4) ((float*)&v)[q] += ons;
            }
            *(float4*)(out + (size_t)kcol*N2 + (size_t)irow*NATOMS + jb) = v;
        }
    }
}

extern "C" void kernel_launch(void* const* d_in, const int* in_sizes, int n_in,
                              void* d_out, int out_size, void* d_ws, size_t ws_size,
                              hipStream_t stream) {
    const float* positions = (const float*)d_in[0];
    const int*   species   = (const int*)d_in[1];
    const float* kpoints   = (const float*)d_in[2];
    const float* param     = (const float*)d_in[3];
    const float* onsite    = (const float*)d_in[4];
    const float* shifts    = (const float*)d_in[5];
    int ns = in_sizes[5] / 3;
    float* out = (float*)d_out;

    dim3 grid((NATOMS/TI) * (NATOMS/TJ));   // 128 * 8 = 1024 blocks
    dftb_mfma<<<grid, NTHREADS, 0, stream>>>(positions, species, kpoints,
                                             param, onsite, shifts, out, ns);
}

// Round 3
// 64.449 us; speedup vs baseline: 1.1384x; 1.1384x over previous
//
#include <hip/hip_runtime.h>

#define NATOMS 512
#define N2 (NATOMS*NATOMS)
#define NKPT 32
#define NPOLY 12
#define NSP 4
#define NSMAX 96            // K padded to 3 x 32
#define KSTR 104            // Tt stride in bf16 (52 dwords; (13*r16+g)%8 distinct per 8-lane phase)
#define TJ 256
#define NTHREADS 256
#define SG_STR 260          // Sg stride in f32 (65 superbanks; (65*r+g)%8 distinct)

typedef __attribute__((ext_vector_type(8))) short bf16x8;
typedef __attribute__((ext_vector_type(4))) float f32x4;

static __device__ __forceinline__ unsigned f2bf2(float lo, float hi) {
    union { float f; unsigned u; } a, b; a.f = lo; b.f = hi;
    unsigned ra = a.u + 0x7FFFu + ((a.u >> 16) & 1u);   // RNE bf16
    unsigned rb = b.u + 0x7FFFu + ((b.u >> 16) & 1u);
    return (ra >> 16) | (rb & 0xFFFF0000u);
}

__global__ __launch_bounds__(NTHREADS, 3)
void dftb3(const float* __restrict__ positions,
           const int* __restrict__ species,
           const float* __restrict__ kpoints,
           const float* __restrict__ param,
           const float* __restrict__ onsite,
           const float* __restrict__ shifts,
           float* __restrict__ out, int ns)
{
    __shared__ unsigned short Tt[64][KSTR];   // B^T: [kcol][s] bf16 (0..31 cos, 32..63 sin)
    __shared__ float Sg[16][SG_STR];          // output transpose staging (16 kcols / pass)
    __shared__ float4 sh4[NSMAX];
    __shared__ float cpar[NSP*NSP*NPOLY];
    __shared__ float4 pjs[TJ];
    __shared__ int sjs[TJ];

    const int tid = threadIdx.x;
    const int bi = blockIdx.x >> 1;          // i row
    const int jt = blockIdx.x & 1;           // j half
    if (ns > NSMAX) ns = NSMAX;

    // ---- phase 0: stage everything (single barrier after) ----
    {
        int j = jt*TJ + tid;
        pjs[tid] = make_float4(positions[j*3], positions[j*3+1], positions[j*3+2], 0.f);
        sjs[tid] = species[j];
    }
    for (int idx = tid; idx < NSP*NSP*NPOLY; idx += NTHREADS) cpar[idx] = param[idx];
    for (int idx = tid; idx < NSMAX; idx += NTHREADS) {
        if (idx < ns) sh4[idx] = make_float4(shifts[idx*3], shifts[idx*3+1], shifts[idx*3+2], 0.f);
        else          sh4[idx] = make_float4(0.f, 0.f, 0.f, 0.f);
    }
    // phase table: Tt[k][s]=cos, Tt[k+32][s]=sin of 2*pi*(kpoints[k]/5).shifts[s]; 0 for s>=ns
    for (int idx = tid; idx < 32*(NSMAX/2); idx += NTHREADS) {
        int k = idx & 31, s2 = idx >> 5;
        float cs[2] = {0.f, 0.f}, sn[2] = {0.f, 0.f};
        #pragma unroll
        for (int h = 0; h < 2; ++h) {
            int s = 2*s2 + h;
            if (s < ns) {
                float d = (kpoints[k*3]*0.2f*shifts[s*3] + kpoints[k*3+1]*0.2f*shifts[s*3+1])
                        + kpoints[k*3+2]*0.2f*shifts[s*3+2];
                sincosf(6.283185307179586f * d, &sn[h], &cs[h]);
            }
        }
        ((unsigned*)&Tt[k][0])[s2]      = f2bf2(cs[0], cs[1]);
        ((unsigned*)&Tt[k+32][0])[s2]   = f2bf2(sn[0], sn[1]);
    }
    __syncthreads();

    const int lane = tid & 63, w = tid >> 6;
    const int r16 = lane & 15, g = lane >> 4;

    // B-frags: lane holds T[kcol=nf*16+r16][k-slice kf*32+g*8 ..+7]
    bf16x8 Bf[4][3];
    #pragma unroll
    for (int nf = 0; nf < 4; ++nf)
        #pragma unroll
        for (int kf = 0; kf < 3; ++kf)
            Bf[nf][kf] = *(const bf16x8*)&Tt[nf*16 + r16][kf*32 + g*8];

    // uniform per-block scalars (compiler: s_loads)
    const float pix = positions[bi*3], piy = positions[bi*3+1], piz = positions[bi*3+2];
    const int   si  = species[bi];
    const float ons = onsite[si];

    f32x4 acc[4][4];
    #pragma unroll
    for (int mf = 0; mf < 4; ++mf)
        #pragma unroll
        for (int nf = 0; nf < 4; ++nf)
            acc[mf][nf] = (f32x4){0.f, 0.f, 0.f, 0.f};

    // ---- main: compute A-frags directly in fragment order, feed MFMA ----
    #pragma unroll
    for (int mf = 0; mf < 4; ++mf) {
        const int jl = w*64 + mf*16 + r16;    // local j this lane's A-row
        const float4 pj = pjs[jl];
        const int sj = sjs[jl];
        float c[NPOLY];
        #pragma unroll
        for (int q = 0; q < NPOLY; ++q) c[q] = cpar[(si*NSP + sj)*NPOLY + q];

        bf16x8 A[3];
        #pragma unroll
        for (int kf = 0; kf < 3; ++kf) {
            unsigned pk[4];
            #pragma unroll
            for (int e2 = 0; e2 < 4; ++e2) {
                float v[2];
                #pragma unroll
                for (int h = 0; h < 2; ++h) {
                    const int s = kf*32 + g*8 + e2*2 + h;
                    float4 sh = sh4[s];
                    // numpy order: (pj + shift) - pi ; (x^2+y^2)+z^2, no FMA contraction
                    float dx = (pj.x + sh.x) - pix;
                    float dy = (pj.y + sh.y) - piy;
                    float dz = (pj.z + sh.z) - piz;
                    float dr2 = (__fmul_rn(dx,dx) + __fmul_rn(dy,dy)) + __fmul_rn(dz,dz);
                    float v_ = 0.f;
                    if (dr2 <= 36.001f && s < ns) {   // conservative prefilter (exact gate below)
                        float dr = sqrtf(dr2);        // correctly-rounded fp32
                        if (dr > 0.1f && dr <= 6.0f) {
                            float x = dr * 1.8897261258369282f;
                            float y = c[NPOLY-1];
                            #pragma unroll
                            for (int q = NPOLY-2; q >= 0; --q) y = fmaf(y, x, c[q]);
                            v_ = y;
                        }
                    }
                    v[h] = v_;
                }
                pk[e2] = f2bf2(v[0], v[1]);
            }
            union { unsigned u[4]; bf16x8 v; } au;
            au.u[0] = pk[0]; au.u[1] = pk[1]; au.u[2] = pk[2]; au.u[3] = pk[3];
            A[kf] = au.v;
        }
        #pragma unroll
        for (int nf = 0; nf < 4; ++nf) {
            acc[mf][nf] = __builtin_amdgcn_mfma_f32_16x16x32_bf16(A[0], Bf[nf][0], acc[mf][nf], 0, 0, 0);
            acc[mf][nf] = __builtin_amdgcn_mfma_f32_16x16x32_bf16(A[1], Bf[nf][1], acc[mf][nf], 0, 0, 0);
            acc[mf][nf] = __builtin_amdgcn_mfma_f32_16x16x32_bf16(A[2], Bf[nf][2], acc[mf][nf], 0, 0, 0);
        }
    }

    // ---- epilogue: LDS transpose (16 kcols/pass) -> 1KB coalesced stores ----
    // D layout: kcol = nf*16 + r16 (lane), jlocal = w*64 + mf*16 + g*4 + reg
    const size_t obase = (size_t)bi*NATOMS + (size_t)jt*TJ;
    #pragma unroll
    for (int nf = 0; nf < 4; ++nf) {
        __syncthreads();                     // Sg free (previous pass fully read)
        #pragma unroll
        for (int mf = 0; mf < 4; ++mf)
            *(float4*)&Sg[r16][w*64 + mf*16 + g*4] = *(float4*)&acc[mf][nf];
        __syncthreads();
        #pragma unroll
        for (int q = 0; q < 4; ++q) {
            const int p = w*4 + q;           // Sg row
            const int kcol = nf*16 + p;      // 0..31 -> Hr plane, 32..63 -> Hi plane
            float4 v = *(float4*)&Sg[p][lane*4];
            if (kcol < 32) {                 // onsite on Hr diagonal
                int d = bi - (jt*TJ + lane*4);
                if (d >= 0 && d < 4) ((float*)&v)[d] += ons;
            }
            *(float4*)(out + (size_t)kcol*N2 + obase + lane*4) = v;
        }
    }
}

extern "C" void kernel_launch(void* const* d_in, const int* in_sizes, int n_in,
                              void* d_out, int out_size, void* d_ws, size_t ws_size,
                              hipStream_t stream) {
    const float* positions = (const float*)d_in[0];
    const int*   species   = (const int*)d_in[1];
    const float* kpoints   = (const float*)d_in[2];
    const float* param     = (const float*)d_in[3];
    const float* onsite    = (const float*)d_in[4];
    const float* shifts    = (const float*)d_in[5];
    int ns = in_sizes[5] / 3;
    float* out = (float*)d_out;

    dim3 grid(NATOMS * (NATOMS/TJ));        // 512 i x 2 j-halves = 1024 blocks
    dftb3<<<grid, NTHREADS, 0, stream>>>(positions, species, kpoints,
                                         param, onsite, shifts, out, ns);
}

// Round 4
// 48.166 us; speedup vs baseline: 1.5232x; 1.3380x over previous
//
#include <hip/hip_runtime.h>

#define NATOMS 512
#define N2 (NATOMS*NATOMS)
#define NKPT 32
#define NPOLY 12
#define NSP 4
#define NSMAX 96            // K padded to 3 x 32
#define TJ 256
#define NTHREADS 256
#define SG_STR 260          // Sg stride in f32

typedef __attribute__((ext_vector_type(8))) short bf16x8;
typedef __attribute__((ext_vector_type(4))) float f32x4;

static __device__ __forceinline__ unsigned f2bf2(float lo, float hi) {
    union { float f; unsigned u; } a, b; a.f = lo; b.f = hi;
    unsigned ra = a.u + 0x7FFFu + ((a.u >> 16) & 1u);   // RNE bf16
    unsigned rb = b.u + 0x7FFFu + ((b.u >> 16) & 1u);
    return (ra >> 16) | (rb & 0xFFFF0000u);
}

// ---- kernel 1: global phase table Ttg[64][96] bf16 ----
// rows 0..31: cos(2*pi*(kpoints[k]/5).shifts[s]) ; rows 32..63: sin. 0 for s>=ns.
__global__ void phase_tab(const float* __restrict__ kpoints,
                          const float* __restrict__ shifts,
                          unsigned* __restrict__ Ttg, int ns)
{
    int idx = blockIdx.x * 256 + threadIdx.x;        // 3072 dwords total
    if (idx >= 64 * 48) return;
    int row = idx / 48, s2 = idx - row * 48;
    int k = row & 31;
    float kcx = kpoints[k*3]   * 0.2f;
    float kcy = kpoints[k*3+1] * 0.2f;
    float kcz = kpoints[k*3+2] * 0.2f;
    float val[2] = {0.f, 0.f};
    #pragma unroll
    for (int h = 0; h < 2; ++h) {
        int s = 2*s2 + h;
        if (s < ns) {
            float d = (kcx*shifts[s*3] + kcy*shifts[s*3+1]) + kcz*shifts[s*3+2];
            float sn, cs;
            sincosf(6.283185307179586f * d, &sn, &cs);
            val[h] = (row >= 32) ? sn : cs;
        }
    }
    Ttg[idx] = f2bf2(val[0], val[1]);
}

// ---- kernel 2: main ----
__global__ __launch_bounds__(NTHREADS, 4)
void dftb4(const float* __restrict__ positions,
           const int* __restrict__ species,
           const float* __restrict__ param,
           const float* __restrict__ onsite,
           const float* __restrict__ shifts,
           const unsigned short* __restrict__ Ttg,
           float* __restrict__ out, int ns)
{
    __shared__ float Sg[16][SG_STR];          // output transpose staging
    __shared__ float4 sh4p[NSMAX + NSMAX/8];  // padded: index s + s/8 -> 4 g-groups in 4 banks
    __shared__ float cpar4[NPOLY*NSP];        // [q][sj] for this block's si
    __shared__ float4 pjs[TJ];
    __shared__ int sjs[TJ];

    const int tid = threadIdx.x;
    const int bi = blockIdx.x >> 1;           // i row
    const int jt = blockIdx.x & 1;            // j half
    if (ns > NSMAX) ns = NSMAX;

    const int si = species[bi];

    // ---- stage (one barrier) ----
    {
        int j = jt*TJ + tid;
        pjs[tid] = make_float4(positions[j*3], positions[j*3+1], positions[j*3+2], 0.f);
        sjs[tid] = species[j];
    }
    if (tid < NPOLY*NSP) {                    // 48: cpar4[q*4+sj]
        int q = tid >> 2, sj = tid & 3;
        cpar4[tid] = param[(si*NSP + sj)*NPOLY + q];
    }
    for (int s = tid; s < NSMAX; s += NTHREADS) {
        float4 v = (s < ns)
            ? make_float4(shifts[s*3], shifts[s*3+1], shifts[s*3+2], 0.f)
            : make_float4(1e9f, 1e9f, 1e9f, 0.f);   // sentinel: dr2 filter rejects
        sh4p[s + (s >> 3)] = v;
    }
    __syncthreads();

    const int lane = tid & 63, w = tid >> 6;
    const int r16 = lane & 15, g = lane >> 4;

    const float pix = positions[bi*3], piy = positions[bi*3+1], piz = positions[bi*3+2];
    const float ons = onsite[si];

    // ---- phase A: A-frags in registers (V in fragment order) ----
    bf16x8 A[4][3];
    #pragma unroll
    for (int mf = 0; mf < 4; ++mf) {
        const int jl = w*64 + mf*16 + r16;    // this lane's A-row (local j)
        const float4 pj = pjs[jl];
        const int sj = sjs[jl];
        float c[NPOLY];
        #pragma unroll
        for (int q = 0; q < NPOLY; ++q) c[q] = cpar4[q*4 + sj];

        #pragma unroll
        for (int kf = 0; kf < 3; ++kf) {
            unsigned pk[4];
            #pragma unroll
            for (int e2 = 0; e2 < 4; ++e2) {
                float v[2];
                #pragma unroll
                for (int h = 0; h < 2; ++h) {
                    const int s = kf*32 + g*8 + e2*2 + h;
                    float4 sh = sh4p[s + (s >> 3)];
                    // numpy order: (pj + shift) - pi ; (x^2+y^2)+z^2, no FMA contraction
                    float dx = (pj.x + sh.x) - pix;
                    float dy = (pj.y + sh.y) - piy;
                    float dz = (pj.z + sh.z) - piz;
                    float dr2 = (__fmul_rn(dx,dx) + __fmul_rn(dy,dy)) + __fmul_rn(dz,dz);
                    float v_ = 0.f;
                    if (dr2 <= 36.001f) {             // conservative prefilter
                        float dr = sqrtf(dr2);        // correctly-rounded fp32
                        if (dr > 0.1f && dr <= 6.0f) {
                            float x = dr * 1.8897261258369282f;
                            float y = c[NPOLY-1];
                            #pragma unroll
                            for (int q = NPOLY-2; q >= 0; --q) y = fmaf(y, x, c[q]);
                            v_ = y;
                        }
                    }
                    v[h] = v_;
                }
                pk[e2] = f2bf2(v[0], v[1]);
            }
            union { unsigned u[4]; bf16x8 v; } au;
            au.u[0] = pk[0]; au.u[1] = pk[1]; au.u[2] = pk[2]; au.u[3] = pk[3];
            A[mf][kf] = au.v;
        }
    }

    // ---- phase B: one kcol-column (16 kcols) at a time; no big live acc ----
    const size_t obase = (size_t)bi*NATOMS + (size_t)jt*TJ;
    #pragma unroll
    for (int nf = 0; nf < 4; ++nf) {
        const unsigned short* tb = Ttg + (size_t)(nf*16 + r16)*NSMAX + g*8;
        bf16x8 B0 = *(const bf16x8*)(tb);
        bf16x8 B1 = *(const bf16x8*)(tb + 32);
        bf16x8 B2 = *(const bf16x8*)(tb + 64);

        f32x4 acc[4];
        #pragma unroll
        for (int mf = 0; mf < 4; ++mf) {
            acc[mf] = (f32x4){0.f, 0.f, 0.f, 0.f};
            acc[mf] = __builtin_amdgcn_mfma_f32_16x16x32_bf16(A[mf][0], B0, acc[mf], 0, 0, 0);
            acc[mf] = __builtin_amdgcn_mfma_f32_16x16x32_bf16(A[mf][1], B1, acc[mf], 0, 0, 0);
            acc[mf] = __builtin_amdgcn_mfma_f32_16x16x32_bf16(A[mf][2], B2, acc[mf], 0, 0, 0);
        }

        __syncthreads();                     // Sg free (previous pass fully read)
        // D layout: kcol(in-nf) = r16, jlocal = w*64 + mf*16 + g*4 + reg
        #pragma unroll
        for (int mf = 0; mf < 4; ++mf)
            *(float4*)&Sg[r16][w*64 + mf*16 + g*4] = *(float4*)&acc[mf];
        __syncthreads();

        #pragma unroll
        for (int q = 0; q < 4; ++q) {
            const int p = w*4 + q;
            const int kcol = nf*16 + p;      // 0..31 -> Hr plane, 32..63 -> Hi plane
            float4 v = *(float4*)&Sg[p][lane*4];
            if (kcol < 32) {                 // onsite on Hr diagonal
                int d = bi - (int)(jt*TJ + lane*4);
                if (d >= 0 && d < 4) ((float*)&v)[d] += ons;
            }
            *(float4*)(out + (size_t)kcol*N2 + obase + lane*4) = v;
        }
    }
}

extern "C" void kernel_launch(void* const* d_in, const int* in_sizes, int n_in,
                              void* d_out, int out_size, void* d_ws, size_t ws_size,
                              hipStream_t stream) {
    const float* positions = (const float*)d_in[0];
    const int*   species   = (const int*)d_in[1];
    const float* kpoints   = (const float*)d_in[2];
    const float* param     = (const float*)d_in[3];
    const float* onsite    = (const float*)d_in[4];
    const float* shifts    = (const float*)d_in[5];
    int ns = in_sizes[5] / 3;
    float* out = (float*)d_out;
    unsigned* Ttg = (unsigned*)d_ws;                 // 64*96*2 = 12 KB

    phase_tab<<<dim3(12), 256, 0, stream>>>(kpoints, shifts, Ttg, ns);
    dim3 grid(NATOMS * (NATOMS/TJ));                 // 1024 blocks
    dftb4<<<grid, NTHREADS, 0, stream>>>(positions, species, param, onsite,
                                         shifts, (const unsigned short*)Ttg, out, ns);
}